// Round 1
// baseline (425.951 us; speedup 1.0000x reference)
//
#include <hip/hip_runtime.h>
#include <hip/hip_bf16.h>

typedef __attribute__((ext_vector_type(4))) int i32x4;
typedef __attribute__((address_space(3))) char lds3;

#define D_IN  4096
#define D_OUT 4096
#define M_TOT 8192
#define RSTRIDE ((size_t)64 * D_IN)   // +64 rows in int8 bytes

// ---- async 16B global->LDS (wave-uniform base + lane*16 dest semantics) ----
__device__ __forceinline__ void async16(const void* g, lds3* l) {
  __builtin_amdgcn_global_load_lds(
      (__attribute__((address_space(1))) void*)g,
      (__attribute__((address_space(3))) void*)l,
      16, 0, 0);
}

// ds_read_b128 via inline asm: invisible to the compiler's waitcnt pass, so no
// auto "s_waitcnt vmcnt(0)" is inserted against outstanding global_load_lds.
#define DSR(dst, addr, off) \
  asm volatile("ds_read_b128 %0, %1 offset:%2" : "=v"(dst) : "v"(addr), "i"(off))

__device__ __forceinline__ int pack4(float a, float b, float c, float d, float s) {
  int q0 = (int)rintf(a * s) & 255;
  int q1 = (int)rintf(b * s) & 255;
  int q2 = (int)rintf(c * s) & 255;
  int q3 = (int)rintf(d * s) & 255;
  return q0 | (q1 << 8) | (q2 << 16) | (q3 << 24);
}

// ---- kernel 1: wave-per-row absmax quantize x -> int8, sx[row] = rowmax/127 ----
// 4 rows/block (one per wave), no LDS, no barriers; butterfly shuffle reduce.
__global__ void quant_x_kernel(const float* __restrict__ x, int* __restrict__ xq,
                               float* __restrict__ sx) {
  const int row = blockIdx.x * 4 + (threadIdx.x >> 6);
  const int lane = threadIdx.x & 63;
  const float4* xr = (const float4*)(x + (size_t)row * D_IN);

  float4 v[16];
  float mx = 0.f;
#pragma unroll
  for (int j = 0; j < 16; j++) {
    v[j] = xr[j * 64 + lane];                       // fully coalesced 16B/lane
    mx = fmaxf(mx, fmaxf(fmaxf(fabsf(v[j].x), fabsf(v[j].y)),
                         fmaxf(fabsf(v[j].z), fabsf(v[j].w))));
  }
#pragma unroll
  for (int off = 32; off; off >>= 1) mx = fmaxf(mx, __shfl_xor(mx, off));
  if (lane == 0) sx[row] = mx * (1.0f / 127.0f);

  const float inv = 127.0f / mx;
  int* xqr = xq + (size_t)row * (D_IN / 4);
#pragma unroll
  for (int j = 0; j < 16; j++)
    xqr[j * 64 + lane] = pack4(v[j].x, v[j].y, v[j].z, v[j].w, inv);
}

// ---- kernel 2: wave-per-row L2 norm (fp64 accum) + quantize W -> int8 ----
__global__ void quant_w_kernel(const float* __restrict__ W, int* __restrict__ wq,
                               float* __restrict__ sn) {
  const int row = blockIdx.x * 4 + (threadIdx.x >> 6);
  const int lane = threadIdx.x & 63;
  const float4* wr = (const float4*)(W + (size_t)row * D_IN);

  float4 v[16];
  double ss = 0.0;
#pragma unroll
  for (int j = 0; j < 16; j++) {
    v[j] = wr[j * 64 + lane];
    ss += (double)v[j].x * v[j].x + (double)v[j].y * v[j].y +
          (double)v[j].z * v[j].z + (double)v[j].w * v[j].w;
  }
#pragma unroll
  for (int off = 32; off; off >>= 1) ss += __shfl_xor(ss, off);
  const float nrm = (float)sqrt(ss);
  if (lane == 0) sn[row] = nrm * (1.0f / 127.0f);

  const float den = nrm + 1e-8f;
  int* wqr = wq + (size_t)row * (D_IN / 4);
#pragma unroll
  for (int j = 0; j < 16; j++) {
    float e[4] = {v[j].x, v[j].y, v[j].z, v[j].w};
    int q[4];
#pragma unroll
    for (int c = 0; c < 4; c++) {
      float wn = e[c] / den;
      wn = fminf(1.0f, fmaxf(-1.0f, wn));
      q[c] = (int)rintf(wn * 127.0f) & 255;
    }
    wqr[j * 64 + lane] = q[0] | (q[1] << 8) | (q[2] << 16) | (q[3] << 24);
  }
}

// ---- GEMM K-loop iteration, 3-stage LDS pipeline + 1-deep register frag pipeline ----
// S = LDS read stage; VM = vmcnt to wait; ISSUE = prefetch stage (S+2)%3;
// MF = run MFMAs on the PREVIOUS iteration's fragments (`use`) while this
// iteration's ds_reads (into `fill`) are in flight.
template<int S, int VM, bool ISSUE, bool MF>
__device__ __forceinline__ void k_pipe(unsigned aA, unsigned aB,
                                       const char*& pA, const char*& pB,
                                       lds3* lA0, lds3* lB0,
                                       i32x4 (&fill)[8], i32x4 (&use)[8],
                                       i32x4 (&acc)[4][4]) {
  asm volatile("s_waitcnt vmcnt(%0)" :: "i"(VM));   // stage S writes landed (per-wave)
  asm volatile("s_barrier" ::: "memory");           // all waves: S ready, S-1 reads done
  if (ISSUE) {                                      // prefetch -> stage (S+2)%3
    constexpr int T = ((S + 2) % 3) * 16384;
    async16(pA, lA0 + T);  async16(pA + RSTRIDE, lA0 + T + 4096);
    async16(pB, lB0 + T);  async16(pB + RSTRIDE, lB0 + T + 4096);
    pA += 64; pB += 64;
  }
  // issue this stage's fragment reads (latency hidden under the MFMAs below)
  DSR(fill[0], aA, S * 16384 + 0);
  DSR(fill[1], aA, S * 16384 + 1024);
  DSR(fill[2], aA, S * 16384 + 2048);
  DSR(fill[3], aA, S * 16384 + 3072);
  DSR(fill[4], aB, S * 16384 + 8192 + 0);
  DSR(fill[5], aB, S * 16384 + 8192 + 1024);
  DSR(fill[6], aB, S * 16384 + 8192 + 2048);
  DSR(fill[7], aB, S * 16384 + 8192 + 3072);
  __builtin_amdgcn_sched_barrier(0);                // pin: reads issued before MFMAs
  if (MF) {
    __builtin_amdgcn_s_setprio(1);
#pragma unroll
    for (int mi = 0; mi < 4; mi++)
#pragma unroll
      for (int ni = 0; ni < 4; ni++)
        acc[mi][ni] = __builtin_amdgcn_mfma_i32_16x16x64_i8(use[mi], use[4 + ni],
                                                            acc[mi][ni], 0, 0, 0);
    __builtin_amdgcn_s_setprio(0);
  }
  __builtin_amdgcn_sched_barrier(0);                // pin: MFMAs before the lgkm wait
  // tie frags through the wait: next iter's MFMAs depend on these outputs
  asm volatile("s_waitcnt lgkmcnt(0)"
               : "+v"(fill[0]), "+v"(fill[1]), "+v"(fill[2]), "+v"(fill[3]),
                 "+v"(fill[4]), "+v"(fill[5]), "+v"(fill[6]), "+v"(fill[7]));
}

// ---- kernel 3: int8 GEMM, C = A @ B^T, epilogue acc*sx[m]*sn[n] + bias[n] ----
// 128x128 tile, BK=64, 4 waves (2x2, 64x64 each), 3-stage LDS pipeline,
// 1-deep register fragment pipeline, one s_barrier/iter, vmcnt never drained
// to 0 until the tail. LDS reads of iter k overlap MFMAs of iter k-1.
__global__ __launch_bounds__(256, 3)
void gemm_i8_kernel(const char* __restrict__ A, const char* __restrict__ B,
                    const float* __restrict__ sx, const float* __restrict__ sn,
                    const float* __restrict__ bias, float* __restrict__ C) {
  __shared__ __align__(16) char smem[3 * 16384];   // stage: A 8KB | B 8KB

  const int t = threadIdx.x;
  const int lane = t & 63;
  const int wave = t >> 6;
  const int wm = wave >> 1, wn = wave & 1;
  const int m0 = blockIdx.y * 128;
  const int n0 = blockIdx.x * 128;

  // staging: thread t fills 16B chunk t (rows 0-63) and t+256 (rows 64-127).
  // LDS slot (row, c) holds global chunk q = (c - ((row&15)>>1)) & 3 so that
  // reads land 2 lanes per bank-class per 16-lane quarter.
  const int srow = t >> 2;
  const int q = ((t & 3) - ((srow & 15) >> 1)) & 3;
  const char* gA = A + (size_t)(m0 + srow) * D_IN + q * 16;
  const char* gB = B + (size_t)(n0 + srow) * D_IN + q * 16;

  lds3* l3 = (lds3*)smem;
  lds3* lA0 = l3 + t * 16;            // stage s: + s*16384
  lds3* lB0 = l3 + 8192 + t * 16;

  // fragment read addresses: lane (ml, g) reads A[row=wX*64+mi*16+ml][k-chunk g]
  // at slot column c = (g + (ml>>1)) & 3; stage/mi offsets via immediates.
  const int ml = lane & 15;
  const int g = lane >> 4;
  const unsigned cperm = (unsigned)((g + (ml >> 1)) & 3);
  const unsigned lds_base = (unsigned)(size_t)l3;
  const unsigned aA = lds_base + (wm * 64 + ml) * 64 + cperm * 16;
  const unsigned aB = lds_base + (wn * 64 + ml) * 64 + cperm * 16;

  i32x4 acc[4][4];
#pragma unroll
  for (int i = 0; i < 4; i++)
#pragma unroll
    for (int j = 0; j < 4; j++) acc[i][j] = (i32x4)0;

  i32x4 fA[8], fB[8];    // double-buffered fragments (A frags 0-3, B frags 4-7)

  // prologue: stage0 (k=0), stage1 (k=64)
  async16(gA, lA0);            async16(gA + RSTRIDE, lA0 + 4096);
  async16(gB, lB0);            async16(gB + RSTRIDE, lB0 + 4096);
  async16(gA + 64, lA0 + 16384);           async16(gA + 64 + RSTRIDE, lA0 + 16384 + 4096);
  async16(gB + 64, lB0 + 16384);           async16(gB + 64 + RSTRIDE, lB0 + 16384 + 4096);

  const char* pA = gA + 128;   // k column for the next issue: (i+2)*64 at i=0
  const char* pB = gB + 128;

  // iters 0..5: prime the register pipeline (iter 0 has no previous frags)
  k_pipe<0, 4, true, false>(aA, aB, pA, pB, lA0, lB0, fA, fB, acc);
  k_pipe<1, 4, true, true >(aA, aB, pA, pB, lA0, lB0, fB, fA, acc);
  k_pipe<2, 4, true, true >(aA, aB, pA, pB, lA0, lB0, fA, fB, acc);
  k_pipe<0, 4, true, true >(aA, aB, pA, pB, lA0, lB0, fB, fA, acc);
  k_pipe<1, 4, true, true >(aA, aB, pA, pB, lA0, lB0, fA, fB, acc);
  k_pipe<2, 4, true, true >(aA, aB, pA, pB, lA0, lB0, fB, fA, acc);

#pragma unroll 1
  for (int tr = 0; tr < 9; ++tr) {      // iters 6..59, period-6 (stage x parity)
    k_pipe<0, 4, true, true>(aA, aB, pA, pB, lA0, lB0, fA, fB, acc);
    k_pipe<1, 4, true, true>(aA, aB, pA, pB, lA0, lB0, fB, fA, acc);
    k_pipe<2, 4, true, true>(aA, aB, pA, pB, lA0, lB0, fA, fB, acc);
    k_pipe<0, 4, true, true>(aA, aB, pA, pB, lA0, lB0, fB, fA, acc);
    k_pipe<1, 4, true, true>(aA, aB, pA, pB, lA0, lB0, fA, fB, acc);
    k_pipe<2, 4, true, true>(aA, aB, pA, pB, lA0, lB0, fB, fA, acc);
  }
  // iters 60..63 (issues for stages 62,63 happen at iters 60,61)
  k_pipe<0, 4, true,  true>(aA, aB, pA, pB, lA0, lB0, fA, fB, acc);
  k_pipe<1, 4, true,  true>(aA, aB, pA, pB, lA0, lB0, fB, fA, acc);
  k_pipe<2, 4, false, true>(aA, aB, pA, pB, lA0, lB0, fA, fB, acc);
  k_pipe<0, 0, false, true>(aA, aB, pA, pB, lA0, lB0, fB, fA, acc);
  // drain: MFMAs on iter 63's fragments (fB)
#pragma unroll
  for (int mi = 0; mi < 4; mi++)
#pragma unroll
    for (int ni = 0; ni < 4; ni++)
      acc[mi][ni] = __builtin_amdgcn_mfma_i32_16x16x64_i8(fB[mi], fB[4 + ni],
                                                          acc[mi][ni], 0, 0, 0);

  // epilogue: D col = lane&15 (n), row = (lane>>4)*4 + reg (m)
  float scn[4], bsv[4];
#pragma unroll
  for (int ni = 0; ni < 4; ni++) {
    const int col = n0 + wn * 64 + ni * 16 + ml;
    scn[ni] = sn[col];
    bsv[ni] = bias[col];
  }
#pragma unroll
  for (int mi = 0; mi < 4; mi++) {
    const int rbase = m0 + wm * 64 + mi * 16 + g * 4;
    float sxv[4];
#pragma unroll
    for (int r = 0; r < 4; r++) sxv[r] = sx[rbase + r];
#pragma unroll
    for (int ni = 0; ni < 4; ni++) {
      const int col = n0 + wn * 64 + ni * 16 + ml;
#pragma unroll
      for (int r = 0; r < 4; r++)
        C[(size_t)(rbase + r) * D_OUT + col] =
            (float)acc[mi][ni][r] * (sxv[r] * scn[ni]) + bsv[ni];
    }
  }
}

extern "C" void kernel_launch(void* const* d_in, const int* in_sizes, int n_in,
                              void* d_out, int out_size, void* d_ws, size_t ws_size,
                              hipStream_t stream) {
  const float* x    = (const float*)d_in[0];   // [4,2048,4096]
  const float* W    = (const float*)d_in[1];   // [4096,4096]
  const float* bias = (const float*)d_in[2];   // [4096]
  float* out = (float*)d_out;                  // [4,2048,4096]

  char* ws = (char*)d_ws;
  char*  xq = ws;                                             // 33.5 MB int8
  char*  wq = ws + (size_t)M_TOT * D_IN;                      // 16.8 MB int8
  float* sx = (float*)(wq + (size_t)D_OUT * D_IN);
  float* sn = sx + M_TOT;

  quant_x_kernel<<<M_TOT / 4, 256, 0, stream>>>(x, (int*)xq, sx);
  quant_w_kernel<<<D_OUT / 4, 256, 0, stream>>>(W, (int*)wq, sn);
  dim3 grid(D_OUT / 128, M_TOT / 128);   // (32, 64)
  gemm_i8_kernel<<<grid, 256, 0, stream>>>(xq, wq, sx, sn, bias, out);
}

// Round 2
// 399.496 us; speedup vs baseline: 1.0662x; 1.0662x over previous
//
#include <hip/hip_runtime.h>

typedef __attribute__((ext_vector_type(4))) int i32x4;
typedef __attribute__((ext_vector_type(16))) int i32x16;
typedef __attribute__((address_space(3))) char lds3;

#define D_IN  4096
#define D_OUT 4096
#define M_TOT 8192

// ---- async 16B global->LDS (wave-uniform base + lane*16 dest semantics) ----
__device__ __forceinline__ void async16(const void* g, lds3* l) {
  __builtin_amdgcn_global_load_lds(
      (__attribute__((address_space(1))) void*)g,
      (__attribute__((address_space(3))) void*)l,
      16, 0, 0);
}

// ds_read_b128 via inline asm: invisible to the compiler's waitcnt pass, so no
// auto "s_waitcnt vmcnt(0)" is inserted against outstanding global_load_lds.
#define DSR(dst, addr, off) \
  asm volatile("ds_read_b128 %0, %1 offset:%2" : "=v"(dst) : "v"(addr), "i"(off))

__device__ __forceinline__ int pack4(float a, float b, float c, float d, float s) {
  int q0 = (int)rintf(a * s) & 255;
  int q1 = (int)rintf(b * s) & 255;
  int q2 = (int)rintf(c * s) & 255;
  int q3 = (int)rintf(d * s) & 255;
  return q0 | (q1 << 8) | (q2 << 16) | (q3 << 24);
}

// ---- kernel 1: wave-per-row absmax quantize x -> int8, sx[row] = rowmax/127 ----
__global__ void quant_x_kernel(const float* __restrict__ x, int* __restrict__ xq,
                               float* __restrict__ sx) {
  const int row = blockIdx.x * 4 + (threadIdx.x >> 6);
  const int lane = threadIdx.x & 63;
  const float4* xr = (const float4*)(x + (size_t)row * D_IN);

  float4 v[16];
  float mx = 0.f;
#pragma unroll
  for (int j = 0; j < 16; j++) {
    v[j] = xr[j * 64 + lane];
    mx = fmaxf(mx, fmaxf(fmaxf(fabsf(v[j].x), fabsf(v[j].y)),
                         fmaxf(fabsf(v[j].z), fabsf(v[j].w))));
  }
#pragma unroll
  for (int off = 32; off; off >>= 1) mx = fmaxf(mx, __shfl_xor(mx, off));
  if (lane == 0) sx[row] = mx * (1.0f / 127.0f);

  const float inv = 127.0f / mx;
  int* xqr = xq + (size_t)row * (D_IN / 4);
#pragma unroll
  for (int j = 0; j < 16; j++)
    xqr[j * 64 + lane] = pack4(v[j].x, v[j].y, v[j].z, v[j].w, inv);
}

// ---- kernel 2: wave-per-row L2 norm (fp64 accum) + quantize W -> int8 ----
__global__ void quant_w_kernel(const float* __restrict__ W, int* __restrict__ wq,
                               float* __restrict__ sn) {
  const int row = blockIdx.x * 4 + (threadIdx.x >> 6);
  const int lane = threadIdx.x & 63;
  const float4* wr = (const float4*)(W + (size_t)row * D_IN);

  float4 v[16];
  double ss = 0.0;
#pragma unroll
  for (int j = 0; j < 16; j++) {
    v[j] = wr[j * 64 + lane];
    ss += (double)v[j].x * v[j].x + (double)v[j].y * v[j].y +
          (double)v[j].z * v[j].z + (double)v[j].w * v[j].w;
  }
#pragma unroll
  for (int off = 32; off; off >>= 1) ss += __shfl_xor(ss, off);
  const float nrm = (float)sqrt(ss);
  if (lane == 0) sn[row] = nrm * (1.0f / 127.0f);

  const float den = nrm + 1e-8f;
  int* wqr = wq + (size_t)row * (D_IN / 4);
#pragma unroll
  for (int j = 0; j < 16; j++) {
    float e[4] = {v[j].x, v[j].y, v[j].z, v[j].w};
    int q[4];
#pragma unroll
    for (int c = 0; c < 4; c++) {
      float wn = e[c] / den;
      wn = fminf(1.0f, fmaxf(-1.0f, wn));
      q[c] = (int)rintf(wn * 127.0f) & 255;
    }
    wqr[j * 64 + lane] = q[0] | (q[1] << 8) | (q[2] << 16) | (q[3] << 24);
  }
}

// ==== 256x256 8-phase i8 GEMM =================================================
// BM=BN=256, BK=128 (128 B rows), 8 waves (2Mx4N, 128x64 per wave),
// mfma_i32_32x32x32_i8, LDS = [A buf0|A buf1|B buf0|B buf1] = 4 x 32 KiB.
// XOR swizzle: stored chunk = c ^ (row&7); staging keeps LDS dest linear and
// pre-swizzles the GLOBAL source chunk (involution), reads apply the same XOR.
// Per K-tile: 4 phases {ds_read subtile; 1 half-tile prefetch; barrier;
// lgkmcnt(0); setprio(1); 8 MFMA; setprio(0); barrier}; vmcnt(4) once per
// K-tile, before phase-4's closing barrier (so cross-wave staging writes are
// barrier-published before the next tile's reads). Liveness: B(buf) freed at
// ph1-bar2 -> B(kt+2) issued ph3/ph4; A(buf) freed at ph4-bar2 -> A(kt+1)
// issued ph1/ph2.
template<int BUF, int VM, bool ISSA, bool ISSB>
__device__ __forceinline__ void ktile(const unsigned (&aAk)[4], const unsigned (&aBk)[4],
                                      const char* pA, const char* pB,
                                      lds3* lA, lds3* lB,
                                      i32x4 (&af)[2][4], i32x4 (&bf)[8],
                                      i32x16 (&acc)[4][2]) {
  constexpr int AB = BUF * 32768;          // this tile's buffer offset
  constexpr int OB = (BUF ^ 1) * 32768;    // other buffer (A(kt+1) target)

  // ---- phase 1: read all B frags + A quarter 0; issue A(kt+1) half 0 ----
  DSR(bf[0], aBk[0], AB + 0);
  DSR(bf[1], aBk[1], AB + 0);
  DSR(bf[2], aBk[2], AB + 0);
  DSR(bf[3], aBk[3], AB + 0);
  DSR(bf[4], aBk[0], AB + 4096);
  DSR(bf[5], aBk[1], AB + 4096);
  DSR(bf[6], aBk[2], AB + 4096);
  DSR(bf[7], aBk[3], AB + 4096);
  DSR(af[0][0], aAk[0], AB + 0);
  DSR(af[0][1], aAk[1], AB + 0);
  DSR(af[0][2], aAk[2], AB + 0);
  DSR(af[0][3], aAk[3], AB + 0);
  if (ISSA) { async16(pA, lA + OB);
              async16(pA + (size_t)64 * D_IN, lA + OB + 8192); }
  asm volatile("s_barrier" ::: "memory");
  asm volatile("s_waitcnt lgkmcnt(0)"
               : "+v"(af[0][0]), "+v"(af[0][1]), "+v"(af[0][2]), "+v"(af[0][3]),
                 "+v"(bf[0]), "+v"(bf[1]), "+v"(bf[2]), "+v"(bf[3]),
                 "+v"(bf[4]), "+v"(bf[5]), "+v"(bf[6]), "+v"(bf[7]));
  __builtin_amdgcn_sched_barrier(0);
  __builtin_amdgcn_s_setprio(1);
#pragma unroll
  for (int kk = 0; kk < 4; kk++) {
    acc[0][0] = __builtin_amdgcn_mfma_i32_32x32x32_i8(af[0][kk], bf[kk],     acc[0][0], 0, 0, 0);
    acc[0][1] = __builtin_amdgcn_mfma_i32_32x32x32_i8(af[0][kk], bf[4 + kk], acc[0][1], 0, 0, 0);
  }
  __builtin_amdgcn_s_setprio(0);
  __builtin_amdgcn_sched_barrier(0);
  asm volatile("s_barrier" ::: "memory");

  // ---- phase 2: A quarter 1; issue A(kt+1) half 1 ----
  DSR(af[1][0], aAk[0], AB + 4096);
  DSR(af[1][1], aAk[1], AB + 4096);
  DSR(af[1][2], aAk[2], AB + 4096);
  DSR(af[1][3], aAk[3], AB + 4096);
  if (ISSA) { async16(pA + (size_t)128 * D_IN, lA + OB + 16384);
              async16(pA + (size_t)192 * D_IN, lA + OB + 24576); }
  asm volatile("s_barrier" ::: "memory");
  asm volatile("s_waitcnt lgkmcnt(0)"
               : "+v"(af[1][0]), "+v"(af[1][1]), "+v"(af[1][2]), "+v"(af[1][3]));
  __builtin_amdgcn_sched_barrier(0);
  __builtin_amdgcn_s_setprio(1);
#pragma unroll
  for (int kk = 0; kk < 4; kk++) {
    acc[1][0] = __builtin_amdgcn_mfma_i32_32x32x32_i8(af[1][kk], bf[kk],     acc[1][0], 0, 0, 0);
    acc[1][1] = __builtin_amdgcn_mfma_i32_32x32x32_i8(af[1][kk], bf[4 + kk], acc[1][1], 0, 0, 0);
  }
  __builtin_amdgcn_s_setprio(0);
  __builtin_amdgcn_sched_barrier(0);
  asm volatile("s_barrier" ::: "memory");

  // ---- phase 3: A quarter 2; issue B(kt+2) half 0 (into THIS buf, freed ph1) ----
  DSR(af[0][0], aAk[0], AB + 8192);
  DSR(af[0][1], aAk[1], AB + 8192);
  DSR(af[0][2], aAk[2], AB + 8192);
  DSR(af[0][3], aAk[3], AB + 8192);
  if (ISSB) { async16(pB, lB + AB);
              async16(pB + (size_t)64 * D_IN, lB + AB + 8192); }
  asm volatile("s_barrier" ::: "memory");
  asm volatile("s_waitcnt lgkmcnt(0)"
               : "+v"(af[0][0]), "+v"(af[0][1]), "+v"(af[0][2]), "+v"(af[0][3]));
  __builtin_amdgcn_sched_barrier(0);
  __builtin_amdgcn_s_setprio(1);
#pragma unroll
  for (int kk = 0; kk < 4; kk++) {
    acc[2][0] = __builtin_amdgcn_mfma_i32_32x32x32_i8(af[0][kk], bf[kk],     acc[2][0], 0, 0, 0);
    acc[2][1] = __builtin_amdgcn_mfma_i32_32x32x32_i8(af[0][kk], bf[4 + kk], acc[2][1], 0, 0, 0);
  }
  __builtin_amdgcn_s_setprio(0);
  __builtin_amdgcn_sched_barrier(0);
  asm volatile("s_barrier" ::: "memory");

  // ---- phase 4: A quarter 3; issue B(kt+2) half 1; vmcnt(VM); barrier ----
  DSR(af[1][0], aAk[0], AB + 12288);
  DSR(af[1][1], aAk[1], AB + 12288);
  DSR(af[1][2], aAk[2], AB + 12288);
  DSR(af[1][3], aAk[3], AB + 12288);
  if (ISSB) { async16(pB + (size_t)128 * D_IN, lB + AB + 16384);
              async16(pB + (size_t)192 * D_IN, lB + AB + 24576); }
  asm volatile("s_barrier" ::: "memory");
  asm volatile("s_waitcnt lgkmcnt(0)"
               : "+v"(af[1][0]), "+v"(af[1][1]), "+v"(af[1][2]), "+v"(af[1][3]));
  __builtin_amdgcn_sched_barrier(0);
  __builtin_amdgcn_s_setprio(1);
#pragma unroll
  for (int kk = 0; kk < 4; kk++) {
    acc[3][0] = __builtin_amdgcn_mfma_i32_32x32x32_i8(af[1][kk], bf[kk],     acc[3][0], 0, 0, 0);
    acc[3][1] = __builtin_amdgcn_mfma_i32_32x32x32_i8(af[1][kk], bf[4 + kk], acc[3][1], 0, 0, 0);
  }
  __builtin_amdgcn_s_setprio(0);
  __builtin_amdgcn_sched_barrier(0);
  asm volatile("s_waitcnt vmcnt(%0)" :: "i"(VM));  // next tile's halves landed...
  asm volatile("s_barrier" ::: "memory");          // ...and published to all waves
}

__global__ __launch_bounds__(512, 2)
void gemm_i8_kernel(const char* __restrict__ A, const char* __restrict__ B,
                    const float* __restrict__ sx, const float* __restrict__ sn,
                    const float* __restrict__ bias, float* __restrict__ C) {
  __shared__ __align__(16) char smem[131072];   // A: 2x32K @0, B: 2x32K @65536

  const int t = threadIdx.x;                    // 512 threads = 8 waves
  const int lane = t & 63;
  const int wave = t >> 6;
  const int wm = wave >> 2, wn = wave & 3;      // 2M x 4N wave grid

  // XCD-aware swizzle (512 wgs, 512%8==0 -> bijective)
  const int bid = blockIdx.x;
  const int swz = ((bid & 7) << 6) | (bid >> 3);
  const int m0 = (swz >> 4) * 256;              // 32 M-tiles
  const int n0 = (swz & 15) * 256;              // 16 N-tiles

  // staging: thread t covers row (h*128 + j*64 + (t>>3)), chunk (t&7);
  // global source chunk pre-swizzled: sch = (t&7) ^ (row&7); LDS dest linear.
  const int srow = t >> 3;
  const int sch  = (t & 7) ^ (srow & 7);
  const char* gA = A + (size_t)(m0 + srow) * D_IN + sch * 16;
  const char* gB = B + (size_t)(n0 + srow) * D_IN + sch * 16;
  lds3* l3 = (lds3*)smem;
  lds3* lA = l3 + t * 16;
  lds3* lB = l3 + 65536 + t * 16;

  // fragment read addrs: row = wX*{128,64} + mi|ni*32 + (lane&31),
  // chunk c = kk*2 + (lane>>5), stored slot = c ^ (row&7) = c ^ (lane&7).
  const int l31 = lane & 31;
  const int hi  = lane >> 5;
  const int e   = lane & 7;
  const unsigned base = (unsigned)(size_t)l3;
  unsigned aAk[4], aBk[4];
#pragma unroll
  for (int kk = 0; kk < 4; kk++) {
    const unsigned sw = (unsigned)(((kk * 2 + hi) ^ e) << 4);
    aAk[kk] = base + (wm * 128 + l31) * 128 + sw;
    aBk[kk] = base + 65536 + (wn * 64 + l31) * 128 + sw;
  }

  i32x16 acc[4][2];
#pragma unroll
  for (int i = 0; i < 4; i++)
#pragma unroll
    for (int j = 0; j < 2; j++) acc[i][j] = (i32x16)0;
  i32x4 af[2][4], bf[8];

  // prologue issue order (vmcnt counting depends on it): B(0), A(0), B(1)
  async16(gB,                       lB);
  async16(gB + (size_t)64  * D_IN,  lB + 8192);
  async16(gB + (size_t)128 * D_IN,  lB + 16384);
  async16(gB + (size_t)192 * D_IN,  lB + 24576);
  async16(gA,                       lA);
  async16(gA + (size_t)64  * D_IN,  lA + 8192);
  async16(gA + (size_t)128 * D_IN,  lA + 16384);
  async16(gA + (size_t)192 * D_IN,  lA + 24576);
  async16(gB + 128,                      lB + 32768);
  async16(gB + 128 + (size_t)64  * D_IN, lB + 32768 + 8192);
  async16(gB + 128 + (size_t)128 * D_IN, lB + 32768 + 16384);
  async16(gB + 128 + (size_t)192 * D_IN, lB + 32768 + 24576);
  asm volatile("s_waitcnt vmcnt(4)");     // B(0)+A(0) landed; B(1) in flight
  asm volatile("s_barrier" ::: "memory"); // published to all waves

  const char* pA = gA + 128;    // at tile kt: issues A(kt+1)
  const char* pB = gB + 256;    // at tile kt: issues B(kt+2)

#pragma unroll 1
  for (int it = 0; it < 15; ++it) {       // K-tiles 0..29
    ktile<0, 4, true, true>(aAk, aBk, pA, pB, lA, lB, af, bf, acc); pA += 128; pB += 128;
    ktile<1, 4, true, true>(aAk, aBk, pA, pB, lA, lB, af, bf, acc); pA += 128; pB += 128;
  }
  // tile 30: issue A(31) only, drain; tile 31: no issues
  ktile<0, 0, true,  false>(aAk, aBk, pA, pB, lA, lB, af, bf, acc); pA += 128;
  ktile<1, 0, false, false>(aAk, aBk, pA, pB, lA, lB, af, bf, acc);

  // epilogue: D layout (32x32): col = lane&31, row = (r&3) + 8*(r>>2) + 4*(lane>>5)
#pragma unroll
  for (int mi = 0; mi < 4; mi++) {
    const int rb = m0 + wm * 128 + mi * 32 + hi * 4;
    float sxv[16];
#pragma unroll
    for (int r = 0; r < 16; r++) sxv[r] = sx[rb + (r & 3) + 8 * (r >> 2)];
#pragma unroll
    for (int ni = 0; ni < 2; ni++) {
      const int col = n0 + wn * 64 + ni * 32 + l31;
      const float scn = sn[col];
      const float bv  = bias[col];
#pragma unroll
      for (int r = 0; r < 16; r++) {
        const int row = rb + (r & 3) + 8 * (r >> 2);
        C[(size_t)row * D_OUT + col] =
            (float)acc[mi][ni][r] * (sxv[r] * scn) + bv;
      }
    }
  }
}

extern "C" void kernel_launch(void* const* d_in, const int* in_sizes, int n_in,
                              void* d_out, int out_size, void* d_ws, size_t ws_size,
                              hipStream_t stream) {
  const float* x    = (const float*)d_in[0];   // [4,2048,4096]
  const float* W    = (const float*)d_in[1];   // [4096,4096]
  const float* bias = (const float*)d_in[2];   // [4096]
  float* out = (float*)d_out;                  // [4,2048,4096]

  char* ws = (char*)d_ws;
  char*  xq = ws;                                             // 33.5 MB int8
  char*  wq = ws + (size_t)M_TOT * D_IN;                      // 16.8 MB int8
  float* sx = (float*)(wq + (size_t)D_OUT * D_IN);
  float* sn = sx + M_TOT;

  quant_x_kernel<<<M_TOT / 4, 256, 0, stream>>>(x, (int*)xq, sx);
  quant_w_kernel<<<D_OUT / 4, 256, 0, stream>>>(W, (int*)wq, sn);
  gemm_i8_kernel<<<512, 512, 0, stream>>>(xq, wq, sx, sn, bias, out);
}